// Round 1
// baseline (290.562 us; speedup 1.0000x reference)
//
#include <hip/hip_runtime.h>
#include <hip/hip_bf16.h>
#include <stdint.h>

// VQ-VAE vector quantizer for MI355X (gfx950)
// z: [32768,256] f32, codebook: [256,8192] f32
// out: z_q [8388608] f32, indices-as-f32 [32768], loss [1]
//
// Pipeline:
//  k_colnorm   : cn[j] = 0.5*sum_d c[d][j]^2
//  k_transpose : cbTf[j][d] = c[d][j]  (f32, for exact refine/gather)
//  k_image     : pre-swizzled bf16 staging image of codebook tiles
//  k_scan      : bf16 MFMA score scan, per-bucket top-2 candidate keys
//  k_refine    : fp64 exact distance over top-5 candidates -> idx, z_q, loss partials
//  k_finish    : loss = 1.25 * sum / 8388608

#define DEVINL __device__ __forceinline__

typedef float f32x4 __attribute__((ext_vector_type(4)));
typedef short short8 __attribute__((ext_vector_type(8)));

#define NROWS   32768
#define DIMS    256
#define NCODES  8192
#define KMIN    ((int)0x80000000)

// ---------------- helpers ----------------
DEVINL unsigned pkbf(float x, float y) {
  unsigned a = __float_as_uint(x); a = (a + 0x7fffu + ((a >> 16) & 1u)) >> 16;
  unsigned b = __float_as_uint(y); b = (b + 0x7fffu + ((b >> 16) & 1u)) >> 16;
  return a | (b << 16);
}

// ---------------- K1: column norms ----------------
__global__ void k_colnorm(const float* __restrict__ cb, float* __restrict__ cn) {
  __shared__ float p[256];
  int j = blockIdx.x * 32 + (threadIdx.x & 31);
  int seg = threadIdx.x >> 5;                 // 8 segments of 32 d
  float s = 0.f;
  for (int i = 0; i < 32; ++i) {
    float v = cb[(size_t)(seg * 32 + i) * NCODES + j];
    s = fmaf(v, v, s);
  }
  p[threadIdx.x] = s;
  __syncthreads();
  if (threadIdx.x < 32) {
    float t = 0.f;
    for (int k = 0; k < 8; ++k) t += p[k * 32 + threadIdx.x];
    cn[j] = 0.5f * t;
  }
}

// ---------------- K2: f32 transpose cbTf[j][d] ----------------
__global__ void k_transpose(const float* __restrict__ cb, float* __restrict__ cbTf) {
  __shared__ float t[64][65];
  int j0 = blockIdx.x * 64, d0 = blockIdx.y * 64;
  int tx = threadIdx.x & 63, ty = threadIdx.x >> 6;   // 4 row-groups
  #pragma unroll
  for (int i = 0; i < 16; ++i) {
    int dl = i * 4 + ty;
    t[dl][tx] = cb[(size_t)(d0 + dl) * NCODES + j0 + tx];
  }
  __syncthreads();
  #pragma unroll
  for (int i = 0; i < 16; ++i) {
    int jl = i * 4 + ty;
    cbTf[(size_t)(j0 + jl) * DIMS + d0 + tx] = t[tx][jl];
  }
}

// ---------------- K3: bf16 pre-swizzled staging image ----------------
// image: [step=128][2048 granules of 16B]; step = tile*8 + chunk (BK=32)
// scan reads granule at byte r*128 + boff with boff pre-XORed by ((r&7)<<4)
__global__ void k_image(const float* __restrict__ cbTf, uint4* __restrict__ img) {
  int g = blockIdx.x * 256 + threadIdx.x;     // 0..262143
  int step = g >> 11;
  int gs = g & 2047;
  int r = gs >> 3;                            // 0..255 (code pair)
  int boff = (gs & 7) * 16;
  int cd = boff ^ ((r & 7) << 4);
  int c_local = 2 * r + (cd >> 6);
  int d0 = (cd & 63) >> 1;                    // multiple of 8
  int tile = step >> 3, chunk = step & 7;
  const float4* s4 = (const float4*)(cbTf + (size_t)(tile * 512 + c_local) * DIMS + chunk * 32 + d0);
  float4 u = s4[0], v = s4[1];
  uint4 o;
  o.x = pkbf(u.x, u.y); o.y = pkbf(u.z, u.w);
  o.z = pkbf(v.x, v.y); o.w = pkbf(v.z, v.w);
  img[g] = o;
}

// ---------------- K4: MFMA scan ----------------
// 256 blocks x 512 threads. Block: 128 rows x all 8192 codes.
// 16 tiles of 512 codes; per tile 8 chunks of BK=32 (double-buffered 32KB).
// Wave grid 2(rows) x 4(codes); wave-tile 64 rows x 128 codes; 16x16x32 frags rf4 x cf8.
__global__ __launch_bounds__(512, 2)
void k_scan(const float* __restrict__ z, const float* __restrict__ cn,
            const uint4* __restrict__ img, int2* __restrict__ cand) {
  __shared__ char smem[131072];               // z 64KB | cb buf0 32KB | cb buf1 32KB
  const int t = threadIdx.x;
  const int lane = t & 63;
  const int wave = t >> 6;
  const int wgr = wave >> 2;                  // row group 0..1
  const int wc  = wave & 3;                   // code group 0..3
  const int l15 = lane & 15;
  const int lgr = lane >> 4;                  // 0..3
  const int brow = blockIdx.x * 128;

  // state: per (rf,ridx) row-slot, top-2 packed keys
  int k1[16], k2[16];
  #pragma unroll
  for (int i = 0; i < 16; ++i) { k1[i] = KMIN; k2[i] = KMIN; }

  // stage z: 128 rows x 256 d f32 -> bf16, XOR-swizzled ((row&31)<<4)
  #pragma unroll
  for (int i = 0; i < 16; ++i) {
    int g = t + i * 512;                      // f32 granule (16B)
    int row = g >> 6, col = g & 63;
    float4 v = *(const float4*)(z + (size_t)(brow + row) * DIMS + col * 4);
    unsigned lo = pkbf(v.x, v.y), hi = pkbf(v.z, v.w);
    int addr = row * 512 + ((col * 8) ^ ((row & 31) << 4));
    *(uint2*)(smem + addr) = make_uint2(lo, hi);
  }

  // prefetch step 0 staging regs
  uint4 stg[4];
  {
    const uint4* g0 = img + wave * 64 + lane;
    #pragma unroll
    for (int i = 0; i < 4; ++i) stg[i] = g0[i * 512];
  }
  __syncthreads();

  f32x4 acc[4][8];

  #pragma unroll 1
  for (int step = 0; step < 128; ++step) {
    const int tile = step >> 3, chunk = step & 7;
    char* cbuf = smem + 65536 + (step & 1) * 32768;

    // commit staged regs (waits on last step's global loads internally)
    {
      char* wbase = cbuf + wave * 1024 + lane * 16;
      #pragma unroll
      for (int i = 0; i < 4; ++i) *(uint4*)(wbase + i * 8192) = stg[i];
    }
    // prefetch next chunk
    if (step < 127) {
      const uint4* gsrc = img + (size_t)(step + 1) * 2048 + wave * 64 + lane;
      #pragma unroll
      for (int i = 0; i < 4; ++i) stg[i] = gsrc[i * 512];
    }
    // tile init: acc = -0.5*||c||^2 so acc ends as score
    if (chunk == 0) {
      #pragma unroll
      for (int cf = 0; cf < 8; ++cf) {
        float h = -cn[tile * 512 + wc * 128 + cf * 16 + l15];
        #pragma unroll
        for (int rf = 0; rf < 4; ++rf) acc[rf][cf] = f32x4{h, h, h, h};
      }
    }
    __syncthreads();

    // fragments
    short8 a[4], b[8];
    #pragma unroll
    for (int rf = 0; rf < 4; ++rf) {
      int m = wgr * 64 + rf * 16 + l15;
      int by = (chunk * 64 + lgr * 16) ^ ((m & 31) << 4);
      a[rf] = *(const short8*)(smem + m * 512 + by);
    }
    #pragma unroll
    for (int cf = 0; cf < 8; ++cf) {
      int c = wc * 128 + cf * 16 + l15;
      int r = c >> 1;
      int by = (((c & 1) << 6) + (lgr << 4)) ^ ((r & 7) << 4);
      b[cf] = *(const short8*)(cbuf + r * 128 + by);
    }
    #pragma unroll
    for (int rf = 0; rf < 4; ++rf) {
      #pragma unroll
      for (int cf = 0; cf < 8; ++cf)
        acc[rf][cf] = __builtin_amdgcn_mfma_f32_16x16x32_bf16(a[rf], b[cf], acc[rf][cf], 0, 0, 0);
    }

    // tile epilogue: insert 8 scores/row into running top-2 (packed int keys)
    if (chunk == 7) {
      int jinvb = 8191 - (tile * 512 + wc * 128 + l15);
      #pragma unroll
      for (int rf = 0; rf < 4; ++rf) {
        #pragma unroll
        for (int cf = 0; cf < 8; ++cf) {
          int jinv = jinvb - cf * 16;
          #pragma unroll
          for (int ridx = 0; ridx < 4; ++ridx) {
            int si = rf * 4 + ridx;
            int iq = (int)(acc[rf][cf][ridx] * 256.0f);
            int k = iq * 8192 + jinv;
            int t1 = max(k1[si], k);
            int t2 = min(k1[si], k);
            k1[si] = t1;
            k2[si] = max(k2[si], t2);
          }
        }
      }
    }
  }

  // write candidates: [row][64 buckets] int2
  #pragma unroll
  for (int rf = 0; rf < 4; ++rf) {
    #pragma unroll
    for (int ridx = 0; ridx < 4; ++ridx) {
      int row = brow + wgr * 64 + rf * 16 + lgr * 4 + ridx;
      int si = rf * 4 + ridx;
      cand[(size_t)row * 64 + wc * 16 + l15] = make_int2(k1[si], k2[si]);
    }
  }
}

// ---------------- K5: exact fp64 refine + outputs + loss partials ----------------
__global__ __launch_bounds__(512)
void k_refine(const float* __restrict__ z, const float* __restrict__ cbTf,
              const int2* __restrict__ cand, float* __restrict__ zq,
              float* __restrict__ oidx, double* __restrict__ parts) {
  __shared__ double lsum[8];
  int lane = threadIdx.x & 63, wave = threadIdx.x >> 6;
  int row = blockIdx.x * 8 + wave;

  float4 z4 = ((const float4*)(z + (size_t)row * DIMS))[lane];
  int2 kp = cand[(size_t)row * 64 + lane];
  int ka = kp.x, kb = kp.y;

  double bd = 1e300; int bj = -1; float4 bc = {0.f, 0.f, 0.f, 0.f};
  for (int s = 0; s < 5; ++s) {
    int km = max(ka, kb);
    #pragma unroll
    for (int m = 1; m < 64; m <<= 1) km = max(km, __shfl_xor(km, m, 64));
    int j = 8191 - (km & 8191);
    if (ka == km) ka = KMIN; else if (kb == km) kb = KMIN;

    float4 c4 = ((const float4*)(cbTf + (size_t)j * DIMS))[lane];
    double dx = (double)z4.x - (double)c4.x;
    double dy = (double)z4.y - (double)c4.y;
    double dzv = (double)z4.z - (double)c4.z;
    double dw = (double)z4.w - (double)c4.w;
    double d = dx * dx + dy * dy + dzv * dzv + dw * dw;
    #pragma unroll
    for (int m = 1; m < 64; m <<= 1) d += __shfl_xor(d, m, 64);

    bool bt = (d < bd) || (d == bd && j < bj);   // wave-uniform
    if (bt) { bd = d; bj = j; bc = c4; }
  }

  ((float4*)(zq + (size_t)row * DIMS))[lane] = bc;
  if (lane == 0) oidx[row] = (float)bj;

  double lx = (double)bc.x - (double)z4.x;
  double ly = (double)bc.y - (double)z4.y;
  double lz = (double)bc.z - (double)z4.z;
  double lw = (double)bc.w - (double)z4.w;
  double l = lx * lx + ly * ly + lz * lz + lw * lw;
  #pragma unroll
  for (int m = 1; m < 64; m <<= 1) l += __shfl_xor(l, m, 64);
  if (lane == 0) lsum[wave] = l;
  __syncthreads();
  if (threadIdx.x == 0) {
    double s = 0;
    for (int i = 0; i < 8; ++i) s += lsum[i];
    parts[blockIdx.x] = s;
  }
}

// ---------------- K6: loss finalize ----------------
__global__ void k_finish(const double* __restrict__ parts, float* __restrict__ out) {
  __shared__ double s[256];
  double a = 0;
  for (int i = threadIdx.x; i < 4096; i += 256) a += parts[i];
  s[threadIdx.x] = a;
  __syncthreads();
  for (int w = 128; w; w >>= 1) {
    if (threadIdx.x < w) s[threadIdx.x] += s[threadIdx.x + w];
    __syncthreads();
  }
  if (threadIdx.x == 0) out[0] = (float)(1.25 * s[0] / 8388608.0);
}

// ---------------- launch ----------------
extern "C" void kernel_launch(void* const* d_in, const int* in_sizes, int n_in,
                              void* d_out, int out_size, void* d_ws, size_t ws_size,
                              hipStream_t stream) {
  const float* zin = (const float*)d_in[0];
  const float* cb  = (const float*)d_in[1];
  float* out = (float*)d_out;

  char* w = (char*)d_ws;
  float*  cn    = (float*)w;                                   // 32 KB
  float*  cbTf  = (float*)(w + 32768);                         // 8 MB
  uint4*  img   = (uint4*)(w + 32768 + 8388608);               // 4 MB
  int2*   cand  = (int2*)(w + 32768 + 8388608 + 4194304);      // 16 MB
  double* parts = (double*)(w + 32768 + 8388608 + 4194304 + 16777216); // 32 KB

  float* zq_out   = out;
  float* idx_out  = out + 8388608;
  float* loss_out = out + 8388608 + 32768;

  k_colnorm<<<dim3(256), dim3(256), 0, stream>>>(cb, cn);
  k_transpose<<<dim3(128, 4), dim3(256), 0, stream>>>(cb, cbTf);
  k_image<<<dim3(1024), dim3(256), 0, stream>>>(cbTf, img);
  k_scan<<<dim3(256), dim3(512), 0, stream>>>(zin, cn, img, cand);
  k_refine<<<dim3(4096), dim3(512), 0, stream>>>(zin, cbTf, cand, zq_out, idx_out, parts);
  k_finish<<<dim3(1), dim3(256), 0, stream>>>(parts, loss_out);
}